// Round 11
// baseline (192.215 us; speedup 1.0000x reference)
//
#include <hip/hip_runtime.h>

// CharBiLSTMEmbedder: N=32768 words, T=20, E=H=50, V=200, out [N,100] fp32.
//
// Round-17: RESUBMIT of round-16 (bench infra failed: "container failed
// twice", same signature as round-12's infra failure which ran clean on
// resubmit; static re-audit found no fault/hang path - coverage exact,
// barriers uniform, bounds/regs verified).
//
// Round-16 design: r9 counters showed occupancy 18% time-avg (launch ==
// capacity, zero backfill; short blocks finish, CUs idle). Fix = STATIC LPT
// PAIRING: 512 blocks x 4 waves; wave w of block b runs sorted group
// g1=(b>>1)*4+w then group 2047-g1 (same dir d=b&1). Uniform(0..20) lengths
// => every wave totals ~21 steps -> no tail; 2 blocks/CU resident full
// duration = 8 waves/CU steady. VGPR/LDS not binding at 2 blocks/CU =>
// G register software-pipeline (next step's 13 int2 loads issue after MFMAs,
// hidden under gate math).
// Carried: barrier-free step loop (wave-private single-buffered h, same-wave
// in-order DS), Wa A-image in LDS, bf16 G from L2, pre-multiplied char
// offsets, exp2-domain gates, counting-sort, launch_bounds(256,1)
// (2nd arg >= 4 forces 64-VGPR squeeze + spill: r1/r8 evidence).

#define TT    20
#define HH    50
#define VV    200
#define TILES 13        // 13*16 = 208 rows >= 200
#define GSTR  212       // G row stride in shorts (53 units * 4 gates)
#define GSH   (VV * GSTR)        // 42400 shorts per dir
#define WSH   (TILES * 16 * 64)  // 13312 shorts per dir
#define NW    32768
#define NB_G  50        // 2 dirs * 25 blocks of 8 emb rows
#define NB_W  104       // ceil(2*WSH/256)
#define NB_H  128       // 128*256 = 32768 words
#define NBLK  512       // 2 dirs * 256 four-wave blocks; 2 groups per wave

#define N2LOG2E (-1.4426950408889634f)
#define P2LOG2E 2.8853900817779268f

typedef __attribute__((ext_vector_type(8))) short bf16x8;
typedef __attribute__((ext_vector_type(4))) float f32x4;

__device__ __forceinline__ float frcp(float x) { return __builtin_amdgcn_rcpf(x); }
#if __has_builtin(__builtin_amdgcn_exp2f)
__device__ __forceinline__ float fexp2(float x) { return __builtin_amdgcn_exp2f(x); }
#else
__device__ __forceinline__ float fexp2(float x) { return exp2f(x); }
#endif

__device__ __forceinline__ short f2bf(float x) {  // RNE fp32 -> bf16
    unsigned b = __builtin_bit_cast(unsigned, x);
    unsigned r = (b + 0x7FFFu + ((b >> 16) & 1u)) >> 16;
    return (short)r;
}
__device__ __forceinline__ float bfhi(unsigned w) {   // high bf16 of dword
    return __builtin_bit_cast(float, w & 0xFFFF0000u);
}
__device__ __forceinline__ float bflo(unsigned w) {   // low bf16 of dword
    return __builtin_bit_cast(float, w << 16);
}

// One kernel, three jobs by block range:
//  [0,NB_G): Gimg[d][v*GSTR+u*4+g] = bf16(sc_g*(emb'[v].W_ih[g*50+u]+b_ih+b_hh))
//            (Wih staged in LDS with sc folded; emb reads wave-uniform)
//  [NB_G,NB_G+NB_W): Wimg = MFMA A-operand image of sc_g*Whh (bf16, k-swizzled)
//  [NB_G+NB_W, +NB_H): cnt[block][21] = length histogram of 256 words
//  sc_g = -log2e for i,f,o rows; +2log2e for g rows (exp2-domain gates).
__global__ void k_prep(const float* __restrict__ emb,
                       const float* __restrict__ Wih_f, const float* __restrict__ bih_f,
                       const float* __restrict__ bhh_f,
                       const float* __restrict__ Wih_b, const float* __restrict__ bih_b,
                       const float* __restrict__ bhh_b,
                       const float* __restrict__ Whh_f, const float* __restrict__ Whh_b,
                       const int* __restrict__ lens,
                       short* __restrict__ Gimg, short* __restrict__ Wimg,
                       int* __restrict__ cnt) {
    int blk = blockIdx.x;
    int tid = threadIdx.x;
    __shared__ float Wl[4 * HH * HH];    // 200x50 f32, pre-scaled (40000 B)
    __shared__ float bs[4 * HH];         // (b_ih+b_hh)*sc

    if (blk < NB_G) {
        int d = blk / 25;
        int vbase = (blk % 25) * 8;
        const float* Wih = d ? Wih_b : Wih_f;
        const float* bih = d ? bih_b : bih_f;
        const float* bhh = d ? bhh_b : bhh_f;
        for (int i = tid; i < 4 * HH * HH; i += 256) {
            int r = i / HH;
            float sc = (r / HH == 2) ? P2LOG2E : N2LOG2E;
            Wl[i] = Wih[i] * sc;
        }
        if (tid < 4 * HH) {
            float sc = (tid / HH == 2) ? P2LOG2E : N2LOG2E;
            bs[tid] = (bih[tid] + bhh[tid]) * sc;
        }
        __syncthreads();
        int r = tid;                      // gate-row 0..199
        if (r < 4 * HH) {
            int g = r / HH, u = r % HH;
            #pragma unroll
            for (int vv = 0; vv < 8; ++vv) {
                int v = vbase + vv;
                float s = bs[r];
                if (v != 0) {             // PAD row of emb is zero
                    #pragma unroll 10
                    for (int e = 0; e < HH; ++e)
                        s = fmaf(emb[v * HH + e], Wl[r * HH + e], s);
                }
                Gimg[d * GSH + v * GSTR + u * 4 + g] = f2bf(s);
            }
        } else {                          // zero pad units u=50..52 (12 shorts/v)
            for (int k = r - 4 * HH; k < 8 * 12; k += 56) {
                int v = vbase + k / 12;
                Gimg[d * GSH + v * GSTR + 4 * HH + (k % 12)] = 0;
            }
        }
    } else if (blk < NB_G + NB_W) {
        int idx = (blk - NB_G) * 256 + tid;
        if (idx >= 2 * WSH) return;
        int d = idx / WSH;
        int e = idx % WSH;
        int t = e >> 10, m = (e >> 6) & 15, k = e & 63;
        int u = 4 * t + (m >> 2), g = m & 3;
        const float* Whh = d ? Whh_b : Whh_f;
        float sc = (g == 2) ? P2LOG2E : N2LOG2E;
        float val = (k < HH && u < HH) ? Whh[(g * HH + u) * HH + k] * sc : 0.0f;
        int ksw = (k & 7) | (((k >> 3) ^ (m & 7)) << 3);
        Wimg[d * WSH + (e & ~63) + ksw] = f2bf(val);
    } else {
        int hb = blk - NB_G - NB_W;      // 0..127
        __shared__ int hcnt[21];
        if (tid < 21) hcnt[tid] = 0;
        __syncthreads();
        atomicAdd(&hcnt[lens[hb * 256 + tid]], 1);
        __syncthreads();
        if (tid < 21) cnt[hb * 21 + tid] = hcnt[tid];
    }
}

// Merged scan+scatter: every block stages the 128x21 histogram into LDS,
// computes its own bucket offsets (buckets ordered L=20..0, LPT), scatters
// its 256 words.
__global__ void k_scat(const int* __restrict__ lens, const int* __restrict__ cnt,
                       int* __restrict__ perm) {
    __shared__ int lcnt[NB_H * 21];     // 10752 B
    __shared__ int part[8][21];
    __shared__ int tot[21];
    __shared__ int cur[21];
    int b = blockIdx.x, t = threadIdx.x;
    for (int i = t; i < NB_H * 21; i += 256) lcnt[i] = cnt[i];
    __syncthreads();
    if (t < 168) {
        int L = t % 21, c = t / 21;
        int s = 0;
        for (int bb = c * 16; bb < c * 16 + 16; ++bb) s += lcnt[bb * 21 + L];
        part[c][L] = s;
    }
    __syncthreads();
    if (t < 21) {
        int a = 0;
        #pragma unroll
        for (int c = 0; c < 8; ++c) a += part[c][t];
        tot[t] = a;
    }
    __syncthreads();
    if (t < 21) {
        int a = 0;
        for (int L2 = 20; L2 > t; --L2) a += tot[L2];   // start of bucket t
        for (int bb = 0; bb < b; ++bb) a += lcnt[bb * 21 + t];
        cur[t] = a;
    }
    __syncthreads();
    int i = b * 256 + t;
    int pos = atomicAdd(&cur[lens[i]], 1);
    perm[pos] = i;
}

// Block = 4 INDEPENDENT waves; wave w runs TWO groups: g1=(b>>1)*4+w (long)
// then 2047-g1 (short) -> every wave totals ~21 steps (uniform lengths).
// h wave-private single-buffered LDS (in-order same-wave DS => no barrier).
// G register-pipelined one step ahead. 2 blocks/CU resident entire kernel.
__launch_bounds__(256, 1)
__global__ void k_lstm(const int* __restrict__ chars, const int* __restrict__ lens,
                       const int* __restrict__ perm,
                       const short* __restrict__ Gimg, const short* __restrict__ Wimg,
                       float* __restrict__ out) {
    __shared__ __align__(16) short Wa[WSH];        // 26624 B (one dir A-image)
    __shared__ __align__(16) short hs[4][1024];    // 8192 B wave-private h
    __shared__ unsigned short cs[4 * 2 * 16 * TT]; // 5120 B char*GSTR offsets

    int b    = blockIdx.x;             // 0..511
    int d    = b & 1;
    int gbase = (b >> 1) * 4;          // first of 4 long groups, 0..1020
    int tid  = threadIdx.x;            // 0..255
    int lane = tid & 63;
    int wv   = __builtin_amdgcn_readfirstlane(tid >> 6);   // 0..3
    int quad = lane >> 4;
    int n    = lane & 15;
    int x7   = n & 7;

    // ---- stage (the only barrier in the kernel is after this) ----
    {
        const int4* src = (const int4*)(Wimg + d * WSH);
        int4* dst = (int4*)Wa;
        for (int i = tid; i < WSH / 8; i += 256) dst[i] = src[i];
    }
    // chars for all 8 (wave, pass) groups: i = w*640 + p*320 + j
    for (int i = tid; i < 4 * 2 * 16 * TT; i += 256) {
        int w = i / 640;
        int p = (i % 640) / 320;
        int j = i % 320;
        int g1 = gbase + w;
        int g = p ? (2047 - g1) : g1;
        int word = perm[g * 16 + j / TT];
        cs[i] = (unsigned short)(chars[word * TT + j % TT] * GSTR);
    }
    __syncthreads();

    int pa0 = quad ^ x7;               // swizzled k-group, k 0..31
    int pa1 = (quad + 4) ^ x7;         // k 32..63

    const bf16x8* ap = (const bf16x8*)Wa;
    short* hw = hs[wv];
    const short* Gq = Gimg + d * GSH + quad * 4;
    int g1 = gbase + wv;

    #pragma unroll 1
    for (int pass = 0; pass < 2; ++pass) {
        int g = pass ? (2047 - g1) : g1;
        int word = perm[g * 16 + n];
        int L = lens[word];
        int mL = L;                     // group max length
        #pragma unroll
        for (int off = 8; off; off >>= 1) {
            int t2 = __shfl_xor(mL, off);
            mL = mL > t2 ? mL : t2;
        }
        mL = __builtin_amdgcn_readfirstlane(mL);

        // zero this wave's h buffer (same-wave DS: ordered before B reads)
        {
            int4 z = {0, 0, 0, 0};
            int4* hz = (int4*)hw;
            hz[lane * 2] = z;
            hz[lane * 2 + 1] = z;
        }

        const unsigned short* cw = cs + wv * 640 + pass * 320 + n * TT;
        float cst[TILES], hf[TILES];
        #pragma unroll
        for (int t = 0; t < TILES; ++t) { cst[t] = 0.0f; hf[t] = 0.0f; }

        int vcur = cw[(d && L > 0) ? (L - 1) : 0];   // pre-multiplied offset
        // G pipeline: step-0 rows loaded before the loop
        int2 gv[TILES];
        {
            const int2* gp = (const int2*)(Gq + vcur);
            #pragma unroll
            for (int tt = 0; tt < TILES; ++tt) gv[tt] = gp[tt * 4];
        }

        #pragma unroll 1
        for (int s = 0; s < mL; ++s) {
            bool valid = s < L;

            bf16x8 B0 = *(const bf16x8*)(hw + n * 64 + pa0 * 8);  // h(s-1)
            bf16x8 B1 = *(const bf16x8*)(hw + n * 64 + pa1 * 8);

            int sn = s + 1;
            int pn = (sn < L) ? (d ? (L - 1 - sn) : sn) : 0;
            int vnxt = cw[pn];

            // pass 1: acc init from pipelined G regs + MFMAs
            f32x4 acc[TILES];
            #pragma unroll
            for (int tt = 0; tt < TILES; ++tt) {
                int2 gw = gv[tt];
                f32x4 a;
                a[0] = bflo((unsigned)gw.x);  // gate i
                a[1] = bfhi((unsigned)gw.x);  // gate f
                a[2] = bflo((unsigned)gw.y);  // gate g
                a[3] = bfhi((unsigned)gw.y);  // gate o
                bf16x8 A0 = ap[(tt * 16 + n) * 8 + pa0];
                bf16x8 A1 = ap[(tt * 16 + n) * 8 + pa1];
                a = __builtin_amdgcn_mfma_f32_16x16x32_bf16(A0, B0, a, 0, 0, 0);
                a = __builtin_amdgcn_mfma_f32_16x16x32_bf16(A1, B1, a, 0, 0, 0);
                acc[tt] = a;
            }
            // issue NEXT step's G loads; latency hides under gate math
            {
                const int2* gp = (const int2*)(Gq + vnxt);
                #pragma unroll
                for (int tt = 0; tt < TILES; ++tt) gv[tt] = gp[tt * 4];
            }
            // pass 2: exp2-domain gates; h written back to wave-private LDS
            #pragma unroll
            for (int tt = 0; tt < TILES; ++tt) {
                float ig = frcp(1.0f + fexp2(acc[tt][0]));
                float fg = frcp(1.0f + fexp2(acc[tt][1]));
                float tg = 1.0f - 2.0f * frcp(1.0f + fexp2(acc[tt][2]));
                float og = frcp(1.0f + fexp2(acc[tt][3]));
                float cn = fg * cst[tt] + ig * tg;
                float hn = og * (1.0f - 2.0f * frcp(1.0f + fexp2(cn * P2LOG2E)));
                int uu = 4 * tt + quad;
                bool upd = valid && (uu < HH);
                cst[tt] = upd ? cn : cst[tt];
                hf[tt]  = upd ? hn : hf[tt];
                if (upd) {   // skipped when invalid -> h frozen (single buffer)
                    int hidx = n * 64 + (((tt >> 1) ^ x7) << 3) + (tt & 1) * 4 + quad;
                    hw[hidx] = f2bf(hn);
                }
            }
        }

        float* orow = out + (size_t)word * (2 * HH) + d * HH;
        #pragma unroll
        for (int tt = 0; tt < TILES; ++tt) {
            int uu = 4 * tt + quad;
            if (uu < HH) orow[uu] = hf[tt];
        }
    }
}

extern "C" void kernel_launch(void* const* d_in, const int* in_sizes, int n_in,
                              void* d_out, int out_size, void* d_ws, size_t ws_size,
                              hipStream_t stream) {
    const int*   chars = (const int*)d_in[0];
    const int*   lens  = (const int*)d_in[1];
    const float* emb   = (const float*)d_in[2];
    const float* Wih_f = (const float*)d_in[3];
    const float* Whh_f = (const float*)d_in[4];
    const float* bih_f = (const float*)d_in[5];
    const float* bhh_f = (const float*)d_in[6];
    const float* Wih_b = (const float*)d_in[7];
    const float* Whh_b = (const float*)d_in[8];
    const float* bih_b = (const float*)d_in[9];
    const float* bhh_b = (const float*)d_in[10];
    float* out = (float*)d_out;

    short* Gimg = (short*)d_ws;                 // 169600 B
    short* Wimg = Gimg + 2 * GSH;               //  53248 B
    int*   cnt  = (int*)(Wimg + 2 * WSH);       //  10752 B
    int*   perm = cnt + NB_H * 21;              // 131072 B   (total ~365 KB)

    k_prep<<<NB_G + NB_W + NB_H, 256, 0, stream>>>(emb, Wih_f, bih_f, bhh_f,
                                                   Wih_b, bih_b, bhh_b,
                                                   Whh_f, Whh_b, lens,
                                                   Gimg, Wimg, cnt);
    k_scat<<<NB_H, 256, 0, stream>>>(lens, cnt, perm);
    k_lstm<<<NBLK, 256, 0, stream>>>(chars, lens, perm, Gimg, Wimg, out);
}

// Round 12
// 153.787 us; speedup vs baseline: 1.2499x; 1.2499x over previous
//
#include <hip/hip_runtime.h>

// CharBiLSTMEmbedder: N=32768 words, T=20, E=H=50, V=200, out [N,100] fp32.
//
// Round-18: back to the proven ISSUE-BOUND regime (r2: 69us, VALUBusy 72%,
// occ 76% via 4x-oversubscribed LPT queue). Ledger findings applied:
//  (1) capacity-exact launches (r7/r9/r11) kill time-avg occupancy (zero
//      backfill) -> keep 4096 blocks, LPT, deep queue.
//  (2) barrier-free needs 136 VGPR -> low TLP -> slower. Abandoned.
//  (3) old 332-block k_prep beats the 50-block LDS-staged one by ~8us
//      (residual 77-78 vs 84-86). Reverted.
// Change vs r2: block = 256 thr / 4 waves, tiles (4,3,3,3) -> total issue
// per group-step 4x78+13x174 = 2574 vs r2's 8x78+13x174 = 2886 (-11%);
// 8 blocks/CU capacity -> 2x queue; 4-wave barrier domain. A-frags read
// straight from L2 (Wimg) like G - no Wa LDS staging (256-thr blocks would
// pay 104 int4 loads each; L2 serves the hot 53KB image to all blocks).
// Tile loop unrolled x4 with wave-uniform (tt<nt) guard (compile-time idx).
// Carried: h dbuf + 1 barrier/step, bf16 G from L2, pre-multiplied char
// offsets, exp2-domain gates, counting-sort LPT, launch_bounds(256,1)
// (2nd arg>=4 forces 64-VGPR squeeze+spill: r1/r8 evidence).

#define TT    20
#define HH    50
#define VV    200
#define TILES 13        // 13*16 = 208 rows >= 200
#define GSTR  212       // G row stride in shorts (53 units * 4 gates)
#define GSH   (VV * GSTR)        // 42400 shorts per dir
#define WSH   (TILES * 16 * 64)  // 13312 shorts per dir
#define NW    32768
#define NB_G  332       // ceil(2*GSH/256)
#define NB_W  104       // ceil(2*WSH/256)
#define NB_H  128       // 128*256 = 32768 words
#define NBLK  4096      // 2 dirs * 2048 groups of 16 words

#define N2LOG2E (-1.4426950408889634f)
#define P2LOG2E 2.8853900817779268f

typedef __attribute__((ext_vector_type(8))) short bf16x8;
typedef __attribute__((ext_vector_type(4))) float f32x4;

__device__ __forceinline__ float frcp(float x) { return __builtin_amdgcn_rcpf(x); }
#if __has_builtin(__builtin_amdgcn_exp2f)
__device__ __forceinline__ float fexp2(float x) { return __builtin_amdgcn_exp2f(x); }
#else
__device__ __forceinline__ float fexp2(float x) { return exp2f(x); }
#endif

__device__ __forceinline__ short f2bf(float x) {  // RNE fp32 -> bf16
    unsigned b = __builtin_bit_cast(unsigned, x);
    unsigned r = (b + 0x7FFFu + ((b >> 16) & 1u)) >> 16;
    return (short)r;
}
__device__ __forceinline__ float bfhi(unsigned w) {   // high bf16 of dword
    return __builtin_bit_cast(float, w & 0xFFFF0000u);
}
__device__ __forceinline__ float bflo(unsigned w) {   // low bf16 of dword
    return __builtin_bit_cast(float, w << 16);
}

// One kernel, three jobs by block range (r2/r4's proven version):
//  [0,NB_G): Gimg[d][v*GSTR+u*4+g] = bf16(sc_g*(emb'[v].W_ih[g*50+u]+b_ih+b_hh))
//  [NB_G,NB_G+NB_W): Wimg = MFMA A-operand image of sc_g*Whh (bf16, k-swizzled)
//  [NB_G+NB_W, +NB_H): cnt[block][21] = length histogram of 256 words
//  sc_g = -log2e for i,f,o rows; +2log2e for g rows (exp2-domain gates).
__global__ void k_prep(const float* __restrict__ emb,
                       const float* __restrict__ Wih_f, const float* __restrict__ bih_f,
                       const float* __restrict__ bhh_f,
                       const float* __restrict__ Wih_b, const float* __restrict__ bih_b,
                       const float* __restrict__ bhh_b,
                       const float* __restrict__ Whh_f, const float* __restrict__ Whh_b,
                       const int* __restrict__ lens,
                       short* __restrict__ Gimg, short* __restrict__ Wimg,
                       int* __restrict__ cnt) {
    int blk = blockIdx.x;
    int tid = threadIdx.x;
    if (blk < NB_G) {
        int idx = blk * 256 + tid;
        if (idx >= 2 * GSH) return;
        int d = idx / GSH;
        int rem = idx % GSH;
        int v = rem / GSTR;
        int u = (rem % GSTR) >> 2;
        int g = idx & 3;
        if (u >= HH) { Gimg[idx] = 0; return; }
        int r = g * HH + u;
        const float* Wih = d ? Wih_b : Wih_f;
        const float* bih = d ? bih_b : bih_f;
        const float* bhh = d ? bhh_b : bhh_f;
        float s = bih[r] + bhh[r];
        if (v != 0) {  // PAD row of emb is zero
            #pragma unroll 10
            for (int e = 0; e < HH; ++e) s = fmaf(emb[v * HH + e], Wih[r * HH + e], s);
        }
        float sc = (g == 2) ? P2LOG2E : N2LOG2E;
        Gimg[idx] = f2bf(s * sc);
    } else if (blk < NB_G + NB_W) {
        int idx = (blk - NB_G) * 256 + tid;
        if (idx >= 2 * WSH) return;
        int d = idx / WSH;
        int e = idx % WSH;
        int t = e >> 10, m = (e >> 6) & 15, k = e & 63;
        int u = 4 * t + (m >> 2), g = m & 3;
        const float* Whh = d ? Whh_b : Whh_f;
        float sc = (g == 2) ? P2LOG2E : N2LOG2E;
        float val = (k < HH && u < HH) ? Whh[(g * HH + u) * HH + k] * sc : 0.0f;
        int ksw = (k & 7) | (((k >> 3) ^ (m & 7)) << 3);
        Wimg[d * WSH + (e & ~63) + ksw] = f2bf(val);
    } else {
        int hb = blk - NB_G - NB_W;      // 0..127
        __shared__ int hcnt[21];
        if (tid < 21) hcnt[tid] = 0;
        __syncthreads();
        atomicAdd(&hcnt[lens[hb * 256 + tid]], 1);
        __syncthreads();
        if (tid < 21) cnt[hb * 21 + tid] = hcnt[tid];
    }
}

// Merged scan+scatter: every block stages the 128x21 histogram into LDS,
// computes its own bucket offsets (buckets ordered L=20..0, LPT), scatters
// its 256 words.
__global__ void k_scat(const int* __restrict__ lens, const int* __restrict__ cnt,
                       int* __restrict__ perm) {
    __shared__ int lcnt[NB_H * 21];     // 10752 B
    __shared__ int part[8][21];
    __shared__ int tot[21];
    __shared__ int cur[21];
    int b = blockIdx.x, t = threadIdx.x;
    for (int i = t; i < NB_H * 21; i += 256) lcnt[i] = cnt[i];
    __syncthreads();
    if (t < 168) {
        int L = t % 21, c = t / 21;
        int s = 0;
        for (int bb = c * 16; bb < c * 16 + 16; ++bb) s += lcnt[bb * 21 + L];
        part[c][L] = s;
    }
    __syncthreads();
    if (t < 21) {
        int a = 0;
        #pragma unroll
        for (int c = 0; c < 8; ++c) a += part[c][t];
        tot[t] = a;
    }
    __syncthreads();
    if (t < 21) {
        int a = 0;
        for (int L2 = 20; L2 > t; --L2) a += tot[L2];   // start of bucket t
        for (int bb = 0; bb < b; ++bb) a += lcnt[bb * 21 + t];
        cur[t] = a;
    }
    __syncthreads();
    int i = b * 256 + t;
    int pos = atomicAdd(&cur[lens[i]], 1);
    perm[pos] = i;
}

// Block = one dir x 16 sorted-adjacent words; 4 waves split the 13 u-tiles
// as (4,3,3,3). h double-buffer in LDS, 1 barrier/step. A and G read from
// L2 (hot ~223KB working set). Tile loop unrolled x4, wave-uniform guard.
__launch_bounds__(256, 1)
__global__ void k_lstm(const int* __restrict__ chars, const int* __restrict__ lens,
                       const int* __restrict__ perm,
                       const short* __restrict__ Gimg, const short* __restrict__ Wimg,
                       float* __restrict__ out) {
    __shared__ __align__(16) short hs[2][1024];    // 4096 B
    __shared__ unsigned short cs[16 * TT];         // 640 B (char*GSTR offsets)

    int gb   = blockIdx.x;             // 0..4095, LPT (longest groups first)
    int d    = gb & 1;
    int grp  = gb >> 1;                // 0..2047
    int tid  = threadIdx.x;            // 0..255
    int lane = tid & 63;
    int wv   = __builtin_amdgcn_readfirstlane(tid >> 6);   // 0..3
    int quad = lane >> 4;
    int n    = lane & 15;
    int x7   = n & 7;
    int slotbase = grp * 16;

    {   // zero both h buffers (4096 B = 256 int4, one per thread)
        int4 z = {0, 0, 0, 0};
        ((int4*)&hs[0][0])[tid] = z;
    }
    for (int i = tid; i < 16 * TT; i += 256) {     // chars as v*GSTR offsets
        int w = perm[slotbase + i / TT];
        cs[i] = (unsigned short)(chars[w * TT + i % TT] * GSTR);
    }

    int word = perm[slotbase + n];
    int L = lens[word];
    int mL = L;                         // block-max length (16-periodic lanes
    #pragma unroll                      //  -> same result in all waves)
    for (int off = 8; off; off >>= 1) {
        int t2 = __shfl_xor(mL, off);
        mL = mL > t2 ? mL : t2;
    }
    mL = __builtin_amdgcn_readfirstlane(mL);

    int pa0 = quad ^ x7;               // swizzled k-group, k 0..31
    int pa1 = (quad + 4) ^ x7;         // k 32..63

    // this wave's tiles: wave 0 -> 0..3 (4), waves 1..3 -> 3 each
    int tb = (wv == 0) ? 0 : (4 + 3 * (wv - 1));   // 0,4,7,10
    int nt = (wv == 0) ? 4 : 3;

    const short* Wd = Wimg + d * WSH;
    const short* Gq = Gimg + d * GSH + quad * 4;
    const unsigned short* cw = cs + n * TT;

    // per-tile loop-invariants (unrolled -> compile-time indices)
    int uu[4], hidx[4];
    const short* Ap0[4];
    const short* Ap1[4];
    #pragma unroll
    for (int tt = 0; tt < 4; ++tt) {
        int tg = tb + tt;
        uu[tt] = 4 * tg + quad;
        hidx[tt] = n * 64 + (((uu[tt] >> 3) ^ x7) << 3) + (uu[tt] & 7);
        Ap0[tt] = Wd + (tg * 16 + n) * 64 + pa0 * 8;
        Ap1[tt] = Wd + (tg * 16 + n) * 64 + pa1 * 8;
    }

    float cst[4], hf[4];
    #pragma unroll
    for (int tt = 0; tt < 4; ++tt) { cst[tt] = 0.0f; hf[tt] = 0.0f; }

    __syncthreads();

    int vcur = cw[(d && L > 0) ? (L - 1) : 0];   // pre-multiplied row offset
    int cur = 0;

    #pragma unroll 1
    for (int s = 0; s < mL; ++s) {
        bool valid = s < L;

        const short* hb = hs[cur];
        bf16x8 B0 = *(const bf16x8*)(hb + n * 64 + pa0 * 8);
        bf16x8 B1 = *(const bf16x8*)(hb + n * 64 + pa1 * 8);

        int sn = s + 1;                 // prefetch next char offset
        int pn = (sn < L) ? (d ? (L - 1 - sn) : sn) : 0;
        int vnxt = cw[pn];

        const int2* gp = (const int2*)(Gq + vcur);
        short* hnb = hs[cur ^ 1];

        #pragma unroll
        for (int tt = 0; tt < 4; ++tt) {
            if (tt < nt) {              // wave-uniform guard (nt from wv)
                int tg = tb + tt;
                int2 gw = gp[tg * 4];   // tg*16 shorts = tg*4 int2, 8B L2
                f32x4 a;
                a[0] = bflo((unsigned)gw.x);  // gate i
                a[1] = bfhi((unsigned)gw.x);  // gate f
                a[2] = bflo((unsigned)gw.y);  // gate g
                a[3] = bfhi((unsigned)gw.y);  // gate o
                bf16x8 A0 = *(const bf16x8*)Ap0[tt];
                bf16x8 A1 = *(const bf16x8*)Ap1[tt];
                a = __builtin_amdgcn_mfma_f32_16x16x32_bf16(A0, B0, a, 0, 0, 0);
                a = __builtin_amdgcn_mfma_f32_16x16x32_bf16(A1, B1, a, 0, 0, 0);

                // exp2-domain gates (scales baked into G/W images)
                float ig = frcp(1.0f + fexp2(a[0]));
                float fg = frcp(1.0f + fexp2(a[1]));
                float tg2 = 1.0f - 2.0f * frcp(1.0f + fexp2(a[2]));
                float og = frcp(1.0f + fexp2(a[3]));
                float cn = fg * cst[tt] + ig * tg2;
                float hn = og * (1.0f - 2.0f * frcp(1.0f + fexp2(cn * P2LOG2E)));

                bool upd = valid && (uu[tt] < HH);
                cst[tt] = upd ? cn : cst[tt];
                hf[tt]  = upd ? hn : hf[tt];
                if (uu[tt] < HH) hnb[hidx[tt]] = f2bf(hf[tt]);  // frozen if invalid
            }
        }

        vcur = vnxt;
        __syncthreads();
        cur ^= 1;
    }

    float* orow = out + (size_t)word * (2 * HH) + d * HH;
    #pragma unroll
    for (int tt = 0; tt < 4; ++tt) {
        if (tt < nt && uu[tt] < HH) orow[uu[tt]] = hf[tt];
    }
}

extern "C" void kernel_launch(void* const* d_in, const int* in_sizes, int n_in,
                              void* d_out, int out_size, void* d_ws, size_t ws_size,
                              hipStream_t stream) {
    const int*   chars = (const int*)d_in[0];
    const int*   lens  = (const int*)d_in[1];
    const float* emb   = (const float*)d_in[2];
    const float* Wih_f = (const float*)d_in[3];
    const float* Whh_f = (const float*)d_in[4];
    const float* bih_f = (const float*)d_in[5];
    const float* bhh_f = (const float*)d_in[6];
    const float* Wih_b = (const float*)d_in[7];
    const float* Whh_b = (const float*)d_in[8];
    const float* bih_b = (const float*)d_in[9];
    const float* bhh_b = (const float*)d_in[10];
    float* out = (float*)d_out;

    short* Gimg = (short*)d_ws;                 // 169600 B
    short* Wimg = Gimg + 2 * GSH;               //  53248 B
    int*   cnt  = (int*)(Wimg + 2 * WSH);       //  10752 B
    int*   perm = cnt + NB_H * 21;              // 131072 B   (total ~365 KB)

    k_prep<<<NB_G + NB_W + NB_H, 256, 0, stream>>>(emb, Wih_f, bih_f, bhh_f,
                                                   Wih_b, bih_b, bhh_b,
                                                   Whh_f, Whh_b, lens,
                                                   Gimg, Wimg, cnt);
    k_scat<<<NB_H, 256, 0, stream>>>(lens, cnt, perm);
    k_lstm<<<NBLK, 256, 0, stream>>>(chars, lens, perm, Gimg, Wimg, out);
}